// Round 1
// baseline (499.788 us; speedup 1.0000x reference)
//
#include <hip/hip_runtime.h>

#define L 1600
#define CCH 64
#define H 80
#define W_ 80
#define HS 40      // downsampled H/W
#define KD 576     // C*3*3
#define KR 1024    // C*4*4
#define NB 4

// ---------------- build W (B,L,576) + norms (B,L) ----------------
__global__ void build_w_kernel(const float* __restrict__ b,
                               float* __restrict__ Wm,
                               float* __restrict__ norms) {
    int bl = blockIdx.x;               // batch*L + l
    int batch = bl / L, l = bl % L;
    int lh = l / HS, lw = l % HS;
    int t = threadIdx.x;               // 0..575
    int c = t / 9, r = t % 9;
    int i = r / 3, j = r % 3;
    int y = lh + i - 1, x = lw + j - 1;   // coords in downsampled f
    float v = 0.f;
    if (y >= 0 && y < HS && x >= 0 && x < HS)
        v = b[((size_t)(batch * CCH + c) * H + 2 * y) * W_ + 2 * x];
    Wm[(size_t)bl * KD + t] = v;

    float s = v * v;
    #pragma unroll
    for (int o = 32; o > 0; o >>= 1) s += __shfl_down(s, o, 64);
    __shared__ float ws[9];
    if ((t & 63) == 0) ws[t >> 6] = s;
    __syncthreads();
    if (t == 0) {
        float tot = 0.f;
        #pragma unroll
        for (int w = 0; w < 9; ++w) tot += ws[w];
        norms[bl] = sqrtf(tot);
    }
}

// ---------------- mm (L) from mask ----------------
__global__ void mm_kernel(const float* __restrict__ mask, float* __restrict__ mmv) {
    int l = blockIdx.x * blockDim.x + threadIdx.x;
    if (l >= L) return;
    int lh = l / HS, lw = l % HS;
    float s = 0.f;
    for (int i = 0; i < 3; ++i)
        for (int j = 0; j < 3; ++j) {
            int y = lh + i - 1, x = lw + j - 1;
            if (y >= 0 && y < HS && x >= 0 && x < HS)
                s += mask[(2 * y) * W_ + 2 * x];
        }
    mmv[l] = ((s / 9.0f) == 0.0f) ? 1.f : 0.f;
}

// ---------------- build R (B,L,1024) ----------------
__global__ void build_r_kernel(const float* __restrict__ b, float* __restrict__ R) {
    size_t idx = (size_t)blockIdx.x * blockDim.x + threadIdx.x;
    if (idx >= (size_t)NB * L * KR) return;
    int d = idx % KR;
    int bl = (int)(idx / KR);
    int l = bl % L, batch = bl / L;
    int c = d >> 4, u = (d >> 2) & 3, v = d & 3;
    int lh = l / HS, lw = l % HS;
    int y = 2 * lh + u - 1, x = 2 * lw + v - 1;
    float val = 0.f;
    if (y >= 0 && y < H && x >= 0 && x < W_)
        val = b[((size_t)(batch * CCH + c) * H + y) * W_ + x];
    R[idx] = val;
}

// ---------------- GEMM1 (NT): Z[p][l] = 10 * dot(W[p],W[l]) / max(norm_l,eps) * mm[l] ----------------
__global__ __launch_bounds__(256) void gemm1_kernel(const float* __restrict__ Wm,
                                                    const float* __restrict__ norms,
                                                    const float* __restrict__ mmv,
                                                    float* __restrict__ Z) {
    int batch = blockIdx.z;
    int p0 = blockIdx.y * 64;
    int l0 = blockIdx.x * 64;
    const float* Wb = Wm + (size_t)batch * L * KD;
    __shared__ float As[16][68];   // k-major, padded
    __shared__ float Bs[16][68];
    int t = threadIdx.x;
    int tx = t & 15, ty = t >> 4;
    int lc = t & 15, lr = t >> 4;
    float acc[4][4] = {};
    for (int k0 = 0; k0 < KD; k0 += 16) {
        #pragma unroll
        for (int it = 0; it < 4; ++it) {
            int r = lr + it * 16;
            As[lc][r] = Wb[(size_t)(p0 + r) * KD + k0 + lc];
            Bs[lc][r] = Wb[(size_t)(l0 + r) * KD + k0 + lc];
        }
        __syncthreads();
        #pragma unroll
        for (int k = 0; k < 16; ++k) {
            float4 av = *reinterpret_cast<const float4*>(&As[k][ty * 4]);
            float4 bv = *reinterpret_cast<const float4*>(&Bs[k][tx * 4]);
            float a[4] = {av.x, av.y, av.z, av.w};
            float bb[4] = {bv.x, bv.y, bv.z, bv.w};
            #pragma unroll
            for (int i = 0; i < 4; ++i)
                #pragma unroll
                for (int j = 0; j < 4; ++j)
                    acc[i][j] = fmaf(a[i], bb[j], acc[i][j]);
        }
        __syncthreads();
    }
    #pragma unroll
    for (int j = 0; j < 4; ++j) {
        int l = l0 + tx * 4 + j;
        float scale = 10.0f / fmaxf(norms[(size_t)batch * L + l], 1e-4f) * mmv[l];
        #pragma unroll
        for (int i = 0; i < 4; ++i) {
            int p = p0 + ty * 4 + i;
            Z[((size_t)batch * L + p) * L + l] = acc[i][j] * scale;
        }
    }
}

// ---------------- row softmax over l (contiguous), then *= mm[l] ----------------
__global__ void softmax_kernel(float* __restrict__ Z, const float* __restrict__ mmv) {
    int row = blockIdx.x;              // batch*L + p
    float* z = Z + (size_t)row * L;
    int t = threadIdx.x;
    __shared__ float red[4];

    float m = -1e30f;
    for (int i = t; i < L; i += 256) m = fmaxf(m, z[i]);
    #pragma unroll
    for (int o = 32; o > 0; o >>= 1) m = fmaxf(m, __shfl_down(m, o, 64));
    if ((t & 63) == 0) red[t >> 6] = m;
    __syncthreads();
    float M = fmaxf(fmaxf(red[0], red[1]), fmaxf(red[2], red[3]));
    __syncthreads();

    float s = 0.f;
    for (int i = t; i < L; i += 256) s += __expf(z[i] - M);
    #pragma unroll
    for (int o = 32; o > 0; o >>= 1) s += __shfl_down(s, o, 64);
    if ((t & 63) == 0) red[t >> 6] = s;
    __syncthreads();
    float S = red[0] + red[1] + red[2] + red[3];
    float inv = 1.0f / S;

    for (int i = t; i < L; i += 256) z[i] = __expf(z[i] - M) * inv * mmv[i];
}

// ---------------- GEMM2 (NN): P2[p][d] = sum_l Z[p][l] * R[l][d] ----------------
__global__ __launch_bounds__(256) void gemm2_kernel(const float* __restrict__ Z,
                                                    const float* __restrict__ R,
                                                    float* __restrict__ P2) {
    int batch = blockIdx.z;
    int p0 = blockIdx.y * 64;
    int d0 = blockIdx.x * 64;
    const float* A = Z + (size_t)batch * L * L;
    const float* Bm = R + (size_t)batch * L * KR;
    __shared__ float As[16][68];   // k-major (transposed store)
    __shared__ float Bs[16][68];   // natural [k][n]
    int t = threadIdx.x;
    int tx = t & 15, ty = t >> 4;
    float acc[4][4] = {};
    for (int k0 = 0; k0 < L; k0 += 16) {
        int lc = t & 15, lr = t >> 4;
        #pragma unroll
        for (int it = 0; it < 4; ++it) {
            int r = lr + it * 16;
            As[lc][r] = A[(size_t)(p0 + r) * L + k0 + lc];
        }
        int bn = t & 63, bk = t >> 6;
        #pragma unroll
        for (int it = 0; it < 4; ++it) {
            int k = bk + it * 4;
            Bs[k][bn] = Bm[(size_t)(k0 + k) * KR + d0 + bn];
        }
        __syncthreads();
        #pragma unroll
        for (int k = 0; k < 16; ++k) {
            float4 av = *reinterpret_cast<const float4*>(&As[k][ty * 4]);
            float4 bv = *reinterpret_cast<const float4*>(&Bs[k][tx * 4]);
            float a[4] = {av.x, av.y, av.z, av.w};
            float bb[4] = {bv.x, bv.y, bv.z, bv.w};
            #pragma unroll
            for (int i = 0; i < 4; ++i)
                #pragma unroll
                for (int j = 0; j < 4; ++j)
                    acc[i][j] = fmaf(a[i], bb[j], acc[i][j]);
        }
        __syncthreads();
    }
    #pragma unroll
    for (int i = 0; i < 4; ++i) {
        int p = p0 + ty * 4 + i;
        #pragma unroll
        for (int j = 0; j < 4; ++j)
            P2[((size_t)batch * L + p) * KR + d0 + tx * 4 + j] = acc[i][j];
    }
}

// ---------------- fold (overlap-add) + crop + /4 ----------------
__global__ void fold_kernel(const float* __restrict__ P2, float* __restrict__ out) {
    size_t idx = (size_t)blockIdx.x * blockDim.x + threadIdx.x;
    if (idx >= (size_t)NB * CCH * H * W_) return;
    int x = (int)(idx % W_);
    int y = (int)((idx / W_) % H);
    int c = (int)((idx / ((size_t)W_ * H)) % CCH);
    int batch = (int)(idx / ((size_t)W_ * H * CCH));
    int yp = y + 1, xp = x + 1;
    float s = 0.f;
    #pragma unroll
    for (int du = 0; du < 2; ++du) {
        int u = (yp & 1) + 2 * du;
        int ph2 = yp - u;
        if (ph2 < 0) continue;
        int ph = ph2 >> 1;
        if (ph >= HS) continue;
        #pragma unroll
        for (int dv = 0; dv < 2; ++dv) {
            int v = (xp & 1) + 2 * dv;
            int pw2 = xp - v;
            if (pw2 < 0) continue;
            int pw = pw2 >> 1;
            if (pw >= HS) continue;
            s += P2[((size_t)batch * L + ph * HS + pw) * KR + c * 16 + u * 4 + v];
        }
    }
    out[idx] = 0.25f * s;
}

extern "C" void kernel_launch(void* const* d_in, const int* in_sizes, int n_in,
                              void* d_out, int out_size, void* d_ws, size_t ws_size,
                              hipStream_t stream) {
    const float* b    = (const float*)d_in[0];
    const float* mask = (const float*)d_in[1];
    float* out = (float*)d_out;

    float* ws    = (float*)d_ws;
    float* Wm    = ws;                     // 4*1600*576   = 3,686,400
    float* norms = Wm + (size_t)NB * L * KD;       // 6,400
    float* mmv   = norms + (size_t)NB * L;         // 1,600
    float* R     = mmv + L;                        // 4*1600*1024 = 6,553,600
    float* Z     = R + (size_t)NB * L * KR;        // 4*1600*1600 = 10,240,000
    float* P2    = Z + (size_t)NB * L * L;         // 6,553,600
    // total ~27,041,600 floats = ~108.2 MB

    build_w_kernel<<<NB * L, 576, 0, stream>>>(b, Wm, norms);
    mm_kernel<<<(L + 255) / 256, 256, 0, stream>>>(mask, mmv);
    build_r_kernel<<<(NB * L * KR + 255) / 256, 256, 0, stream>>>(b, R);
    gemm1_kernel<<<dim3(25, 25, NB), 256, 0, stream>>>(Wm, norms, mmv, Z);
    softmax_kernel<<<NB * L, 256, 0, stream>>>(Z, mmv);
    gemm2_kernel<<<dim3(16, 25, NB), 256, 0, stream>>>(Z, R, P2);
    fold_kernel<<<((size_t)NB * CCH * H * W_ + 255) / 256, 256, 0, stream>>>(P2, out);
}

// Round 2
// 134.044 us; speedup vs baseline: 3.7285x; 3.7285x over previous
//
#include <hip/hip_runtime.h>
#include <hip/hip_bf16.h>

#define L 1600
#define LP 1664          // 13*128 padded
#define CCH 64
#define H 80
#define W_ 80
#define HS 40
#define KD 576           // C*3*3
#define KR 1024          // C*4*4
#define NB 4

typedef __hip_bfloat16 bf16;
typedef short bfrag __attribute__((ext_vector_type(8)));   // 8 bf16 (4 VGPR)
typedef float f32x4 __attribute__((ext_vector_type(4)));

__device__ __forceinline__ void gload16(const void* g, void* l) {
    __builtin_amdgcn_global_load_lds(
        (const __attribute__((address_space(1))) unsigned int*)g,
        (__attribute__((address_space(3))) unsigned int*)l, 16, 0, 0);
}

// ---------------- build W (B,LP,576) bf16 + norms (B,LP) ----------------
__global__ void build_w_kernel(const float* __restrict__ b,
                               bf16* __restrict__ Wm,
                               float* __restrict__ norms) {
    int bl = blockIdx.x;               // batch*LP + l
    int batch = bl / LP, l = bl % LP;
    int t = threadIdx.x;               // 0..575
    if (l >= L) {                      // pad rows: zero
        Wm[(size_t)bl * KD + t] = __float2bfloat16(0.f);
        if (t == 0) norms[bl] = 1.f;
        return;
    }
    int lh = l / HS, lw = l % HS;
    int c = t / 9, r = t % 9;
    int i = r / 3, j = r % 3;
    int y = lh + i - 1, x = lw + j - 1;
    float v = 0.f;
    if (y >= 0 && y < HS && x >= 0 && x < HS)
        v = b[((size_t)(batch * CCH + c) * H + 2 * y) * W_ + 2 * x];
    Wm[(size_t)bl * KD + t] = __float2bfloat16(v);

    float s = v * v;
    #pragma unroll
    for (int o = 32; o > 0; o >>= 1) s += __shfl_down(s, o, 64);
    __shared__ float ws[9];
    if ((t & 63) == 0) ws[t >> 6] = s;
    __syncthreads();
    if (t == 0) {
        float tot = 0.f;
        #pragma unroll
        for (int w = 0; w < 9; ++w) tot += ws[w];
        norms[bl] = sqrtf(tot);
    }
}

// ---------------- mm (LP) from mask ----------------
__global__ void mm_kernel(const float* __restrict__ mask, float* __restrict__ mmv) {
    int l = blockIdx.x * blockDim.x + threadIdx.x;
    if (l >= LP) return;
    if (l >= L) { mmv[l] = 0.f; return; }
    int lh = l / HS, lw = l % HS;
    float s = 0.f;
    for (int i = 0; i < 3; ++i)
        for (int j = 0; j < 3; ++j) {
            int y = lh + i - 1, x = lw + j - 1;
            if (y >= 0 && y < HS && x >= 0 && x < HS)
                s += mask[(2 * y) * W_ + 2 * x];
        }
    mmv[l] = ((s / 9.0f) == 0.0f) ? 1.f : 0.f;
}

// ---------------- build R transposed: Rt (B,1024,LP) bf16 ----------------
__global__ void build_rt_kernel(const float* __restrict__ b, bf16* __restrict__ Rt) {
    size_t idx = (size_t)blockIdx.x * blockDim.x + threadIdx.x;
    if (idx >= (size_t)NB * KR * LP) return;
    int l = (int)(idx % LP);
    int rest = (int)(idx / LP);
    int d = rest % KR, batch = rest / KR;
    float val = 0.f;
    if (l < L) {
        int c = d >> 4, u = (d >> 2) & 3, v = d & 3;
        int lh = l / HS, lw = l % HS;
        int y = 2 * lh + u - 1, x = 2 * lw + v - 1;
        if (y >= 0 && y < H && x >= 0 && x < W_)
            val = b[((size_t)(batch * CCH + c) * H + y) * W_ + x];
    }
    Rt[idx] = __float2bfloat16(val);
}

// ---------------- NT bf16 MFMA GEMM: C[m][n] = sum_k A[m][k]*B[n][k] ----------------
// 128x128 tile, BK=64, 4 waves (2x2 of 64x64), global_load_lds + XOR swizzle.
// LDS tile layout: [128 rows][64 bf16 = 128 B = 8 slots of 16 B], slot' = slot ^ (row&7).
__device__ __forceinline__ void stage_tile(const char* gbase, size_t strideB,
                                           char* lds, int wave, int lane) {
    #pragma unroll
    for (int it = 0; it < 4; ++it) {
        int cb = it * 256 + wave * 64;        // wave-uniform chunk base
        int c = cb + lane;
        int row = c >> 3, s = c & 7;
        const char* g = gbase + (size_t)row * strideB + ((s ^ (row & 7)) << 4);
        gload16(g, lds + (size_t)cb * 16);
    }
}

template<int KTOT, int MODE>
__global__ __launch_bounds__(256) void gemm_nt(
    const bf16* __restrict__ A, int sA, size_t batchA,
    const bf16* __restrict__ B, int sB, size_t batchB,
    const float* __restrict__ norms, const float* __restrict__ mmv,
    bf16* __restrict__ outBf, float* __restrict__ outF,
    int sOut, size_t batchOut) {
    __shared__ __align__(128) bf16 As[128 * 64];
    __shared__ __align__(128) bf16 Bs[128 * 64];
    int t = threadIdx.x;
    int lane = t & 63, wave = t >> 6;
    int wm = wave >> 1, wn = wave & 1;
    int batch = blockIdx.z;
    int m0 = blockIdx.y * 128, n0 = blockIdx.x * 128;

    const char* Ag = (const char*)(A + (size_t)batch * batchA + (size_t)m0 * sA);
    const char* Bg = (const char*)(B + (size_t)batch * batchB + (size_t)n0 * sB);
    size_t sAb = (size_t)sA * 2, sBb = (size_t)sB * 2;

    f32x4 acc[4][4] = {};
    for (int k0 = 0; k0 < KTOT; k0 += 64) {
        stage_tile(Ag + (size_t)k0 * 2, sAb, (char*)As, wave, lane);
        stage_tile(Bg + (size_t)k0 * 2, sBb, (char*)Bs, wave, lane);
        __syncthreads();
        #pragma unroll
        for (int h = 0; h < 2; ++h) {
            bfrag af[4], bfv[4];
            #pragma unroll
            for (int mi = 0; mi < 4; ++mi) {
                int r = wm * 64 + mi * 16 + (lane & 15);
                int sl = (h * 4 + (lane >> 4)) ^ (r & 7);
                af[mi] = *(const bfrag*)((const char*)As + r * 128 + sl * 16);
            }
            #pragma unroll
            for (int nj = 0; nj < 4; ++nj) {
                int r = wn * 64 + nj * 16 + (lane & 15);
                int sl = (h * 4 + (lane >> 4)) ^ (r & 7);
                bfv[nj] = *(const bfrag*)((const char*)Bs + r * 128 + sl * 16);
            }
            #pragma unroll
            for (int mi = 0; mi < 4; ++mi)
                #pragma unroll
                for (int nj = 0; nj < 4; ++nj)
                    acc[mi][nj] = __builtin_amdgcn_mfma_f32_16x16x32_bf16(
                        af[mi], bfv[nj], acc[mi][nj], 0, 0, 0);
        }
        __syncthreads();
    }

    // C/D layout (verified m89): col = lane&15, row = (lane>>4)*4 + jj
    if (MODE == 0) {
        bf16* outb = outBf + (size_t)batch * batchOut;
        const float* nr = norms + (size_t)batch * LP;
        #pragma unroll
        for (int nj = 0; nj < 4; ++nj) {
            int col = n0 + wn * 64 + nj * 16 + (lane & 15);
            float scale = 10.0f / fmaxf(nr[col], 1e-4f) * mmv[col];
            #pragma unroll
            for (int mi = 0; mi < 4; ++mi)
                #pragma unroll
                for (int jj = 0; jj < 4; ++jj) {
                    int p = m0 + wm * 64 + mi * 16 + (lane >> 4) * 4 + jj;
                    outb[(size_t)p * sOut + col] = __float2bfloat16(acc[mi][nj][jj] * scale);
                }
        }
    } else {
        float* outf = outF + (size_t)batch * batchOut;
        #pragma unroll
        for (int nj = 0; nj < 4; ++nj) {
            int col = n0 + wn * 64 + nj * 16 + (lane & 15);
            #pragma unroll
            for (int mi = 0; mi < 4; ++mi)
                #pragma unroll
                for (int jj = 0; jj < 4; ++jj) {
                    int p = m0 + wm * 64 + mi * 16 + (lane >> 4) * 4 + jj;
                    outf[(size_t)p * sOut + col] = acc[mi][nj][jj];
                }
        }
    }
}

// ---------------- row softmax over l, then *= mm[l] (bf16 in place) ----------------
__global__ void softmax_kernel(bf16* __restrict__ Zb, const float* __restrict__ mmv) {
    int r = blockIdx.x;                 // batch*L + p
    int batch = r / L, p = r % L;
    bf16* z = Zb + ((size_t)batch * LP + p) * LP;
    int t = threadIdx.x;
    __shared__ float red[4];

    float v[7];
    float m = -1e30f;
    #pragma unroll
    for (int i = 0; i < 7; ++i) {
        int idx = t + i * 256;
        v[i] = (idx < L) ? __bfloat162float(z[idx]) : -1e30f;
        m = fmaxf(m, v[i]);
    }
    #pragma unroll
    for (int o = 32; o > 0; o >>= 1) m = fmaxf(m, __shfl_down(m, o, 64));
    if ((t & 63) == 0) red[t >> 6] = m;
    __syncthreads();
    float M = fmaxf(fmaxf(red[0], red[1]), fmaxf(red[2], red[3]));
    __syncthreads();

    float e[7];
    float s = 0.f;
    #pragma unroll
    for (int i = 0; i < 7; ++i) { e[i] = __expf(v[i] - M); s += e[i]; }
    #pragma unroll
    for (int o = 32; o > 0; o >>= 1) s += __shfl_down(s, o, 64);
    if ((t & 63) == 0) red[t >> 6] = s;
    __syncthreads();
    float S = red[0] + red[1] + red[2] + red[3];
    float inv = 1.0f / S;

    #pragma unroll
    for (int i = 0; i < 7; ++i) {
        int idx = t + i * 256;
        if (idx < L) z[idx] = __float2bfloat16(e[i] * inv * mmv[idx]);
    }
}

// ---------------- fold (overlap-add) + crop + /4 ----------------
__global__ void fold_kernel(const float* __restrict__ P2, float* __restrict__ out) {
    size_t idx = (size_t)blockIdx.x * blockDim.x + threadIdx.x;
    if (idx >= (size_t)NB * CCH * H * W_) return;
    int x = (int)(idx % W_);
    int y = (int)((idx / W_) % H);
    int c = (int)((idx / ((size_t)W_ * H)) % CCH);
    int batch = (int)(idx / ((size_t)W_ * H * CCH));
    int yp = y + 1, xp = x + 1;
    float s = 0.f;
    #pragma unroll
    for (int du = 0; du < 2; ++du) {
        int u = (yp & 1) + 2 * du;
        int ph2 = yp - u;
        if (ph2 < 0) continue;
        int ph = ph2 >> 1;
        if (ph >= HS) continue;
        #pragma unroll
        for (int dv = 0; dv < 2; ++dv) {
            int v = (xp & 1) + 2 * dv;
            int pw2 = xp - v;
            if (pw2 < 0) continue;
            int pw = pw2 >> 1;
            if (pw >= HS) continue;
            s += P2[((size_t)batch * LP + ph * HS + pw) * KR + c * 16 + u * 4 + v];
        }
    }
    out[idx] = 0.25f * s;
}

extern "C" void kernel_launch(void* const* d_in, const int* in_sizes, int n_in,
                              void* d_out, int out_size, void* d_ws, size_t ws_size,
                              hipStream_t stream) {
    const float* b    = (const float*)d_in[0];
    const float* mask = (const float*)d_in[1];
    float* out = (float*)d_out;

    char* w = (char*)d_ws;
    bf16* Wb = (bf16*)w;  w += (size_t)NB * LP * KD * 2;   // 7.7 MB
    bf16* Rt = (bf16*)w;  w += (size_t)NB * KR * LP * 2;   // 13.6 MB
    bf16* Zb = (bf16*)w;  w += (size_t)NB * LP * LP * 2;   // 22.2 MB
    float* P2 = (float*)w; w += (size_t)NB * LP * KR * 4;  // 27.3 MB
    float* norms = (float*)w; w += (size_t)NB * LP * 4;
    float* mmv = (float*)w;   w += (size_t)LP * 4;
    // total ~70.8 MB

    build_w_kernel<<<NB * LP, KD, 0, stream>>>(b, Wb, norms);
    mm_kernel<<<(LP + 255) / 256, 256, 0, stream>>>(mask, mmv);
    build_rt_kernel<<<(int)(((size_t)NB * KR * LP + 255) / 256), 256, 0, stream>>>(b, Rt);

    // GEMM1: Z[p][l] = 10*dot(W_p,W_l)/max(norm_l)*mm_l  -> bf16 Zb [B][LP][LP]
    gemm_nt<KD, 0><<<dim3(13, 13, NB), 256, 0, stream>>>(
        Wb, KD, (size_t)LP * KD,
        Wb, KD, (size_t)LP * KD,
        norms, mmv, Zb, nullptr, LP, (size_t)LP * LP);

    softmax_kernel<<<NB * L, 256, 0, stream>>>(Zb, mmv);

    // GEMM2: P2[p][d] = sum_l Zb[p][l] * Rt[d][l]  -> f32 P2 [B][LP][KR]
    gemm_nt<L, 1><<<dim3(8, 13, NB), 256, 0, stream>>>(
        Zb, LP, (size_t)LP * LP,
        Rt, LP, (size_t)KR * LP,
        nullptr, nullptr, nullptr, P2, KR, (size_t)LP * KR);

    fold_kernel<<<(int)(((size_t)NB * CCH * H * W_ + 255) / 256), 256, 0, stream>>>(P2, out);
}

// Round 3
// 115.882 us; speedup vs baseline: 4.3129x; 1.1567x over previous
//
#include <hip/hip_runtime.h>
#include <hip/hip_bf16.h>

#define L 1600
#define LP 1664          // 13*128
#define CCH 64
#define H 80
#define W_ 80
#define HS 40
#define KD 576           // C*3*3
#define KR 1024          // C*4*4
#define NB 4
#define NT1 13
#define MT1 13
#define NT2 8
#define MT2 13

typedef __hip_bfloat16 bf16;
typedef short bfrag __attribute__((ext_vector_type(8)));
typedef float f32x4 __attribute__((ext_vector_type(4)));

__device__ __forceinline__ void gload16(const void* g, void* l) {
    __builtin_amdgcn_global_load_lds(
        (const __attribute__((address_space(1))) unsigned int*)g,
        (__attribute__((address_space(3))) unsigned int*)l, 16, 0, 0);
}

// bijective XCD swizzle (m204): orig -> wgid so consecutive wgid share an XCD
__device__ __forceinline__ int xcd_wgid(int orig, int nwg) {
    int q = nwg >> 3, r = nwg & 7;
    int xcd = orig & 7, iw = orig >> 3;
    return (xcd < r) ? xcd * (q + 1) + iw : r * (q + 1) + (xcd - r) * q + iw;
}

// ---------------- build W (B,LP,576) bf16 + norms (B,LP) ----------------
__global__ void build_w_kernel(const float* __restrict__ b,
                               bf16* __restrict__ Wm,
                               float* __restrict__ norms) {
    int bl = blockIdx.x;
    int batch = bl / LP, l = bl % LP;
    int t = threadIdx.x;               // 0..575
    if (l >= L) {
        Wm[(size_t)bl * KD + t] = __float2bfloat16(0.f);
        if (t == 0) norms[bl] = 1.f;
        return;
    }
    int lh = l / HS, lw = l % HS;
    int c = t / 9, r = t % 9;
    int i = r / 3, j = r % 3;
    int y = lh + i - 1, x = lw + j - 1;
    float v = 0.f;
    if (y >= 0 && y < HS && x >= 0 && x < HS)
        v = b[((size_t)(batch * CCH + c) * H + 2 * y) * W_ + 2 * x];
    Wm[(size_t)bl * KD + t] = __float2bfloat16(v);

    float s = v * v;
    #pragma unroll
    for (int o = 32; o > 0; o >>= 1) s += __shfl_down(s, o, 64);
    __shared__ float ws[9];
    if ((t & 63) == 0) ws[t >> 6] = s;
    __syncthreads();
    if (t == 0) {
        float tot = 0.f;
        #pragma unroll
        for (int w = 0; w < 9; ++w) tot += ws[w];
        norms[bl] = sqrtf(tot);
    }
}

// ---------------- mm (LP) from mask ----------------
__global__ void mm_kernel(const float* __restrict__ mask, float* __restrict__ mmv) {
    int l = blockIdx.x * blockDim.x + threadIdx.x;
    if (l >= LP) return;
    if (l >= L) { mmv[l] = 0.f; return; }
    int lh = l / HS, lw = l % HS;
    float s = 0.f;
    for (int i = 0; i < 3; ++i)
        for (int j = 0; j < 3; ++j) {
            int y = lh + i - 1, x = lw + j - 1;
            if (y >= 0 && y < HS && x >= 0 && x < HS)
                s += mask[(2 * y) * W_ + 2 * x];
        }
    mmv[l] = ((s / 9.0f) == 0.0f) ? 1.f : 0.f;
}

// ---------------- build R transposed: Rt (B,1024,LP) bf16 ----------------
__global__ void build_rt_kernel(const float* __restrict__ b, bf16* __restrict__ Rt) {
    size_t idx = (size_t)blockIdx.x * blockDim.x + threadIdx.x;
    if (idx >= (size_t)NB * KR * LP) return;
    int l = (int)(idx % LP);
    int rest = (int)(idx / LP);
    int d = rest % KR, batch = rest / KR;
    float val = 0.f;
    if (l < L) {
        int c = d >> 4, u = (d >> 2) & 3, v = d & 3;
        int lh = l / HS, lw = l % HS;
        int y = 2 * lh + u - 1, x = 2 * lw + v - 1;
        if (y >= 0 && y < H && x >= 0 && x < W_)
            val = b[((size_t)(batch * CCH + c) * H + y) * W_ + x];
    }
    Rt[idx] = __float2bfloat16(val);
}

// LDS tile: [128 rows][64 bf16 = 8 slots of 16B], slot' = slot ^ (row&7)
__device__ __forceinline__ void stage_tile(const char* gbase, size_t strideB,
                                           char* lds, int wave, int lane) {
    #pragma unroll
    for (int it = 0; it < 4; ++it) {
        int cb = it * 256 + wave * 64;
        int c = cb + lane;
        int row = c >> 3, s = c & 7;
        const char* g = gbase + (size_t)row * strideB + ((s ^ (row & 7)) << 4);
        gload16(g, lds + (size_t)cb * 16);
    }
}

// ---------------- GEMM1 (NT) + exp epilogue: E = exp(z - 10*norm_p)*mm, Sp row-sums ----------------
__global__ __launch_bounds__(256) void gemm1_kernel(
    const bf16* __restrict__ Wm, const float* __restrict__ norms,
    const float* __restrict__ mmv, bf16* __restrict__ E, float* __restrict__ Sp) {
    __shared__ __align__(128) bf16 As[128 * 64];
    __shared__ __align__(128) bf16 Bs[128 * 64];
    __shared__ float Ssh[2][128];
    int t = threadIdx.x, lane = t & 63, wave = t >> 6;
    int wm = wave >> 1, wn = wave & 1;
    const int nwg = NT1 * MT1 * NB;
    int wgid = xcd_wgid(blockIdx.x, nwg);
    int n = wgid % NT1, m = (wgid / NT1) % MT1, batch = wgid / (NT1 * MT1);
    int m0 = m * 128, n0 = n * 128;

    const char* Ag = (const char*)(Wm + ((size_t)batch * LP + m0) * KD);
    const char* Bg = (const char*)(Wm + ((size_t)batch * LP + n0) * KD);
    const size_t sKD = (size_t)KD * 2;

    f32x4 acc[4][4] = {};
    for (int k0 = 0; k0 < KD; k0 += 64) {
        stage_tile(Ag + (size_t)k0 * 2, sKD, (char*)As, wave, lane);
        stage_tile(Bg + (size_t)k0 * 2, sKD, (char*)Bs, wave, lane);
        __syncthreads();
        #pragma unroll
        for (int h = 0; h < 2; ++h) {
            bfrag af[4], bfv[4];
            #pragma unroll
            for (int mi = 0; mi < 4; ++mi) {
                int r = wm * 64 + mi * 16 + (lane & 15);
                int sl = (h * 4 + (lane >> 4)) ^ (r & 7);
                af[mi] = *(const bfrag*)((const char*)As + r * 128 + sl * 16);
            }
            #pragma unroll
            for (int nj = 0; nj < 4; ++nj) {
                int r = wn * 64 + nj * 16 + (lane & 15);
                int sl = (h * 4 + (lane >> 4)) ^ (r & 7);
                bfv[nj] = *(const bfrag*)((const char*)Bs + r * 128 + sl * 16);
            }
            #pragma unroll
            for (int mi = 0; mi < 4; ++mi)
                #pragma unroll
                for (int nj = 0; nj < 4; ++nj)
                    acc[mi][nj] = __builtin_amdgcn_mfma_f32_16x16x32_bf16(
                        af[mi], bfv[nj], acc[mi][nj], 0, 0, 0);
        }
        __syncthreads();
    }

    const float* nr = norms + (size_t)batch * LP;
    bf16* Eb = E + (size_t)batch * LP * LP;
    float rs[4][4];
    #pragma unroll
    for (int mi = 0; mi < 4; ++mi)
        #pragma unroll
        for (int jj = 0; jj < 4; ++jj) rs[mi][jj] = 0.f;

    float Mp[4][4];
    #pragma unroll
    for (int mi = 0; mi < 4; ++mi)
        #pragma unroll
        for (int jj = 0; jj < 4; ++jj) {
            int p = m0 + wm * 64 + mi * 16 + (lane >> 4) * 4 + jj;
            Mp[mi][jj] = 10.0f * nr[p];
        }

    #pragma unroll
    for (int nj = 0; nj < 4; ++nj) {
        int l = n0 + wn * 64 + nj * 16 + (lane & 15);
        float mml = mmv[l];
        float sc = 10.0f / fmaxf(nr[l], 1e-4f) * mml;
        float vld = (l < L) ? 1.f : 0.f;
        #pragma unroll
        for (int mi = 0; mi < 4; ++mi)
            #pragma unroll
            for (int jj = 0; jj < 4; ++jj) {
                int p = m0 + wm * 64 + mi * 16 + (lane >> 4) * 4 + jj;
                float e = __expf(acc[mi][nj][jj] * sc - Mp[mi][jj]);
                rs[mi][jj] += e * vld;
                Eb[(size_t)p * LP + l] = __float2bfloat16(e * mml);
            }
    }

    #pragma unroll
    for (int mi = 0; mi < 4; ++mi)
        #pragma unroll
        for (int jj = 0; jj < 4; ++jj) {
            float v = rs[mi][jj];
            v += __shfl_xor(v, 1, 64);
            v += __shfl_xor(v, 2, 64);
            v += __shfl_xor(v, 4, 64);
            v += __shfl_xor(v, 8, 64);
            if ((lane & 15) == 0)
                Ssh[wn][wm * 64 + mi * 16 + (lane >> 4) * 4 + jj] = v;
        }
    __syncthreads();
    if (t < 128)
        Sp[(size_t)n * (NB * LP) + (size_t)batch * LP + m0 + t] = Ssh[0][t] + Ssh[1][t];
}

// ---------------- GEMM2 (NT): P2[p][d] = (sum_l E[p][l]*Rt[d][l]) / S[p], bf16 out ----------------
__global__ __launch_bounds__(256) void gemm2_kernel(
    const bf16* __restrict__ E, const bf16* __restrict__ Rt,
    const float* __restrict__ Sp, bf16* __restrict__ P2) {
    __shared__ __align__(128) bf16 As[128 * 64];
    __shared__ __align__(128) bf16 Bs[128 * 64];
    __shared__ float invS[128];
    int t = threadIdx.x, lane = t & 63, wave = t >> 6;
    int wm = wave >> 1, wn = wave & 1;
    const int nwg = NT2 * MT2 * NB;
    int wgid = xcd_wgid(blockIdx.x, nwg);
    int n = wgid % NT2, m = (wgid / NT2) % MT2, batch = wgid / (NT2 * MT2);
    int m0 = m * 128, n0 = n * 128;

    if (t < 128) {
        float s = 0.f;
        #pragma unroll
        for (int nt = 0; nt < NT1; ++nt)
            s += Sp[(size_t)nt * (NB * LP) + (size_t)batch * LP + m0 + t];
        invS[t] = 1.0f / s;
    }

    const char* Ag = (const char*)(E + ((size_t)batch * LP + m0) * LP);
    const char* Bg = (const char*)(Rt + ((size_t)batch * KR + n0) * LP);
    const size_t sLP = (size_t)LP * 2;

    f32x4 acc[4][4] = {};
    for (int k0 = 0; k0 < L; k0 += 64) {
        stage_tile(Ag + (size_t)k0 * 2, sLP, (char*)As, wave, lane);
        stage_tile(Bg + (size_t)k0 * 2, sLP, (char*)Bs, wave, lane);
        __syncthreads();
        #pragma unroll
        for (int h = 0; h < 2; ++h) {
            bfrag af[4], bfv[4];
            #pragma unroll
            for (int mi = 0; mi < 4; ++mi) {
                int r = wm * 64 + mi * 16 + (lane & 15);
                int sl = (h * 4 + (lane >> 4)) ^ (r & 7);
                af[mi] = *(const bfrag*)((const char*)As + r * 128 + sl * 16);
            }
            #pragma unroll
            for (int nj = 0; nj < 4; ++nj) {
                int r = wn * 64 + nj * 16 + (lane & 15);
                int sl = (h * 4 + (lane >> 4)) ^ (r & 7);
                bfv[nj] = *(const bfrag*)((const char*)Bs + r * 128 + sl * 16);
            }
            #pragma unroll
            for (int mi = 0; mi < 4; ++mi)
                #pragma unroll
                for (int nj = 0; nj < 4; ++nj)
                    acc[mi][nj] = __builtin_amdgcn_mfma_f32_16x16x32_bf16(
                        af[mi], bfv[nj], acc[mi][nj], 0, 0, 0);
        }
        __syncthreads();
    }

    bf16* outb = P2 + (size_t)batch * LP * KR;
    #pragma unroll
    for (int nj = 0; nj < 4; ++nj) {
        int d = n0 + wn * 64 + nj * 16 + (lane & 15);
        #pragma unroll
        for (int mi = 0; mi < 4; ++mi)
            #pragma unroll
            for (int jj = 0; jj < 4; ++jj) {
                int pl = wm * 64 + mi * 16 + (lane >> 4) * 4 + jj;
                outb[(size_t)(m0 + pl) * KR + d] =
                    __float2bfloat16(acc[mi][nj][jj] * invS[pl]);
            }
    }
}

// ---------------- fold (overlap-add) + crop + /4 ----------------
__global__ void fold_kernel(const bf16* __restrict__ P2, float* __restrict__ out) {
    size_t idx = (size_t)blockIdx.x * blockDim.x + threadIdx.x;
    if (idx >= (size_t)NB * CCH * H * W_) return;
    int x = (int)(idx % W_);
    int y = (int)((idx / W_) % H);
    int c = (int)((idx / ((size_t)W_ * H)) % CCH);
    int batch = (int)(idx / ((size_t)W_ * H * CCH));
    int yp = y + 1, xp = x + 1;
    float s = 0.f;
    #pragma unroll
    for (int du = 0; du < 2; ++du) {
        int u = (yp & 1) + 2 * du;
        int ph2 = yp - u;
        if (ph2 < 0) continue;
        int ph = ph2 >> 1;
        if (ph >= HS) continue;
        #pragma unroll
        for (int dv = 0; dv < 2; ++dv) {
            int v = (xp & 1) + 2 * dv;
            int pw2 = xp - v;
            if (pw2 < 0) continue;
            int pw = pw2 >> 1;
            if (pw >= HS) continue;
            s += __bfloat162float(
                P2[((size_t)batch * LP + ph * HS + pw) * KR + c * 16 + u * 4 + v]);
        }
    }
    out[idx] = 0.25f * s;
}

extern "C" void kernel_launch(void* const* d_in, const int* in_sizes, int n_in,
                              void* d_out, int out_size, void* d_ws, size_t ws_size,
                              hipStream_t stream) {
    const float* b    = (const float*)d_in[0];
    const float* mask = (const float*)d_in[1];
    float* out = (float*)d_out;

    char* w = (char*)d_ws;
    bf16* Wb = (bf16*)w;  w += (size_t)NB * LP * KD * 2;   // 7.7 MB
    bf16* Rt = (bf16*)w;  w += (size_t)NB * KR * LP * 2;   // 13.6 MB
    bf16* E  = (bf16*)w;  w += (size_t)NB * LP * LP * 2;   // 22.2 MB
    bf16* P2 = (bf16*)w;  w += (size_t)NB * LP * KR * 2;   // 13.6 MB
    float* norms = (float*)w; w += (size_t)NB * LP * 4;
    float* mmv = (float*)w;   w += (size_t)LP * 4;
    float* Sp = (float*)w;    w += (size_t)NT1 * NB * LP * 4;  // 346 KB
    // total ~58 MB

    build_w_kernel<<<NB * LP, KD, 0, stream>>>(b, Wb, norms);
    mm_kernel<<<(LP + 255) / 256, 256, 0, stream>>>(mask, mmv);
    build_rt_kernel<<<(int)(((size_t)NB * KR * LP + 255) / 256), 256, 0, stream>>>(b, Rt);

    gemm1_kernel<<<NT1 * MT1 * NB, 256, 0, stream>>>(Wb, norms, mmv, E, Sp);
    gemm2_kernel<<<NT2 * MT2 * NB, 256, 0, stream>>>(E, Rt, Sp, P2);

    fold_kernel<<<(int)(((size_t)NB * CCH * H * W_ + 255) / 256), 256, 0, stream>>>(P2, out);
}

// Round 4
// 115.548 us; speedup vs baseline: 4.3254x; 1.0029x over previous
//
#include <hip/hip_runtime.h>
#include <hip/hip_bf16.h>

#define L 1600
#define LP 1664          // 13*128
#define CCH 64
#define H 80
#define W_ 80
#define HS 40
#define KD 576           // C*3*3
#define KR 1024          // C*4*4
#define NB 4
#define NT1 13
#define NT2 8
#define MT2 13
#define NPAIR 91         // NT1*(NT1+1)/2

typedef __hip_bfloat16 bf16;
typedef short bfrag __attribute__((ext_vector_type(8)));
typedef float f32x4 __attribute__((ext_vector_type(4)));
typedef short short4_t __attribute__((ext_vector_type(4)));
typedef short short8_t __attribute__((ext_vector_type(8)));

__device__ __forceinline__ void gload16(const void* g, void* l) {
    __builtin_amdgcn_global_load_lds(
        (const __attribute__((address_space(1))) unsigned int*)g,
        (__attribute__((address_space(3))) unsigned int*)l, 16, 0, 0);
}

// bijective XCD swizzle (m204)
__device__ __forceinline__ int xcd_wgid(int orig, int nwg) {
    int q = nwg >> 3, r = nwg & 7;
    int xcd = orig & 7, iw = orig >> 3;
    return (xcd < r) ? xcd * (q + 1) + iw : r * (q + 1) + (xcd - r) * q + iw;
}

// ---------------- build W (B,LP,576) bf16 + norms (B,LP) ----------------
__global__ void build_w_kernel(const float* __restrict__ b,
                               bf16* __restrict__ Wm,
                               float* __restrict__ norms) {
    int bl = blockIdx.x;
    int batch = bl / LP, l = bl % LP;
    int t = threadIdx.x;               // 0..575
    if (l >= L) {
        Wm[(size_t)bl * KD + t] = __float2bfloat16(0.f);
        if (t == 0) norms[bl] = 1.f;
        return;
    }
    int lh = l / HS, lw = l % HS;
    int c = t / 9, r = t % 9;
    int i = r / 3, j = r % 3;
    int y = lh + i - 1, x = lw + j - 1;
    float v = 0.f;
    if (y >= 0 && y < HS && x >= 0 && x < HS)
        v = b[((size_t)(batch * CCH + c) * H + 2 * y) * W_ + 2 * x];
    Wm[(size_t)bl * KD + t] = __float2bfloat16(v);

    float s = v * v;
    #pragma unroll
    for (int o = 32; o > 0; o >>= 1) s += __shfl_down(s, o, 64);
    __shared__ float ws[9];
    if ((t & 63) == 0) ws[t >> 6] = s;
    __syncthreads();
    if (t == 0) {
        float tot = 0.f;
        #pragma unroll
        for (int w = 0; w < 9; ++w) tot += ws[w];
        norms[bl] = sqrtf(tot);
    }
}

// ---------------- mm (LP) from mask ----------------
__global__ void mm_kernel(const float* __restrict__ mask, float* __restrict__ mmv) {
    int l = blockIdx.x * blockDim.x + threadIdx.x;
    if (l >= LP) return;
    if (l >= L) { mmv[l] = 0.f; return; }
    int lh = l / HS, lw = l % HS;
    float s = 0.f;
    for (int i = 0; i < 3; ++i)
        for (int j = 0; j < 3; ++j) {
            int y = lh + i - 1, x = lw + j - 1;
            if (y >= 0 && y < HS && x >= 0 && x < HS)
                s += mask[(2 * y) * W_ + 2 * x];
        }
    mmv[l] = ((s / 9.0f) == 0.0f) ? 1.f : 0.f;
}

// ---------------- build R transposed: Rt (B,1024,LP) bf16, short8 stores ----------------
__global__ void build_rt_kernel(const float* __restrict__ b, bf16* __restrict__ Rt) {
    int idx = blockIdx.x * 256 + threadIdx.x;      // NB*KR*(LP/8) threads
    int lp = idx % (LP / 8);
    int rest = idx / (LP / 8);
    int d = rest % KR, batch = rest / KR;
    int l8 = lp * 8;
    short8_t pack = {};
    if (l8 < L) {
        int c = d >> 4, u = (d >> 2) & 3, v = d & 3;
        int lh = l8 / HS, lw0 = l8 % HS;           // 8 | 40 -> pack never crosses a row
        int y = 2 * lh + u - 1;
        if (y >= 0 && y < H) {
            const float* row = b + ((size_t)(batch * CCH + c) * H + y) * W_;
            #pragma unroll
            for (int j = 0; j < 8; ++j) {
                int x = 2 * (lw0 + j) + v - 1;
                float val = (x >= 0 && x < W_) ? row[x] : 0.f;
                bf16 hv = __float2bfloat16(val);
                pack[j] = *reinterpret_cast<short*>(&hv);
            }
        }
    }
    *reinterpret_cast<short8_t*>(Rt + ((size_t)batch * KR + d) * LP + l8) = pack;
}

// LDS tile: [128 rows][64 bf16 = 8 slots of 16B], slot' = slot ^ (row&7)
__device__ __forceinline__ void stage_tile(const char* gbase, size_t strideB,
                                           char* lds, int wave, int lane) {
    #pragma unroll
    for (int it = 0; it < 4; ++it) {
        int cb = it * 256 + wave * 64;
        int c = cb + lane;
        int row = c >> 3, s = c & 7;
        const char* g = gbase + (size_t)row * strideB + ((s ^ (row & 7)) << 4);
        gload16(g, lds + (size_t)cb * 16);
    }
}

// ---------------- GEMM1 triangular (m<=n): one dot -> both E[p][l] and E[l][p] ----------------
__global__ __launch_bounds__(256) void gemm1_kernel(
    const bf16* __restrict__ Wm, const float* __restrict__ norms,
    const float* __restrict__ mmv, bf16* __restrict__ E, float* __restrict__ Sp) {
    __shared__ __align__(128) bf16 As[128 * 64];
    __shared__ __align__(128) bf16 Bs[128 * 64];
    __shared__ float Ssh[2][128];   // e1 row-sums  [wn][p-idx]
    __shared__ float Ssh2[2][128];  // e2 row-sums  [wm][l-idx]
    int tid = threadIdx.x, lane = tid & 63, wave = tid >> 6;
    int wm = wave >> 1, wn = wave & 1;
    const int nwg = NB * NPAIR;
    int wgid = xcd_wgid(blockIdx.x, nwg);
    int batch = wgid / NPAIR;
    int t91 = wgid % NPAIR;
    int m = 0;
    while (t91 >= NT1 - m) { t91 -= NT1 - m; ++m; }
    int n = m + t91;
    bool diag = (m == n);
    int m0 = m * 128, n0 = n * 128;

    const char* Ag = (const char*)(Wm + ((size_t)batch * LP + m0) * KD);
    const char* Bg = (const char*)(Wm + ((size_t)batch * LP + n0) * KD);
    const size_t sKD = (size_t)KD * 2;

    f32x4 acc[4][4] = {};
    for (int k0 = 0; k0 < KD; k0 += 64) {
        stage_tile(Ag + (size_t)k0 * 2, sKD, (char*)As, wave, lane);
        stage_tile(Bg + (size_t)k0 * 2, sKD, (char*)Bs, wave, lane);
        __syncthreads();
        #pragma unroll
        for (int h = 0; h < 2; ++h) {
            bfrag af[4], bfv[4];
            #pragma unroll
            for (int mi = 0; mi < 4; ++mi) {
                int r = wm * 64 + mi * 16 + (lane & 15);
                int sl = (h * 4 + (lane >> 4)) ^ (r & 7);
                af[mi] = *(const bfrag*)((const char*)As + r * 128 + sl * 16);
            }
            #pragma unroll
            for (int nj = 0; nj < 4; ++nj) {
                int r = wn * 64 + nj * 16 + (lane & 15);
                int sl = (h * 4 + (lane >> 4)) ^ (r & 7);
                bfv[nj] = *(const bfrag*)((const char*)Bs + r * 128 + sl * 16);
            }
            #pragma unroll
            for (int mi = 0; mi < 4; ++mi)
                #pragma unroll
                for (int nj = 0; nj < 4; ++nj)
                    acc[mi][nj] = __builtin_amdgcn_mfma_f32_16x16x32_bf16(
                        af[mi], bfv[nj], acc[mi][nj], 0, 0, 0);
        }
        __syncthreads();
    }

    const float* nr = norms + (size_t)batch * LP;
    bf16* Eb = E + (size_t)batch * LP * LP;

    // p-side (row) constants
    float Mp[4][4], scp[4][4], mmp[4][4], vldp[4][4];
    #pragma unroll
    for (int mi = 0; mi < 4; ++mi)
        #pragma unroll
        for (int jj = 0; jj < 4; ++jj) {
            int p = m0 + wm * 64 + mi * 16 + (lane >> 4) * 4 + jj;
            float np = nr[p];
            float mp = mmv[p];
            Mp[mi][jj] = 10.0f * np;
            scp[mi][jj] = 10.0f / fmaxf(np, 1e-4f) * mp;
            mmp[mi][jj] = mp;
            vldp[mi][jj] = (p < L) ? 1.f : 0.f;
        }

    float rs1[4][4] = {};
    float rs2[4] = {};

    #pragma unroll
    for (int nj = 0; nj < 4; ++nj) {
        int l = n0 + wn * 64 + nj * 16 + (lane & 15);
        float nl = nr[l];
        float mml = mmv[l];
        float scl = 10.0f / fmaxf(nl, 1e-4f) * mml;
        float Ml = 10.0f * nl;
        float vldl = (l < L) ? 1.f : 0.f;
        #pragma unroll
        for (int mi = 0; mi < 4; ++mi) {
            short4_t pk = {};
            #pragma unroll
            for (int jj = 0; jj < 4; ++jj) {
                float dotv = acc[mi][nj][jj];
                int p = m0 + wm * 64 + mi * 16 + (lane >> 4) * 4 + jj;
                float e1 = __expf(dotv * scl - Mp[mi][jj]);
                rs1[mi][jj] += e1 * vldl;
                Eb[(size_t)p * LP + l] = __float2bfloat16(e1 * mml);
                if (!diag) {
                    float e2 = __expf(dotv * scp[mi][jj] - Ml);
                    rs2[nj] += e2 * vldp[mi][jj];
                    bf16 hv = __float2bfloat16(e2 * mmp[mi][jj]);
                    pk[jj] = *reinterpret_cast<short*>(&hv);
                }
            }
            if (!diag) {
                int p0v = m0 + wm * 64 + mi * 16 + (lane >> 4) * 4;
                *reinterpret_cast<short4_t*>(Eb + (size_t)l * LP + p0v) = pk;
            }
        }
    }

    #pragma unroll
    for (int mi = 0; mi < 4; ++mi)
        #pragma unroll
        for (int jj = 0; jj < 4; ++jj) {
            float v = rs1[mi][jj];
            v += __shfl_xor(v, 1, 64);
            v += __shfl_xor(v, 2, 64);
            v += __shfl_xor(v, 4, 64);
            v += __shfl_xor(v, 8, 64);
            if ((lane & 15) == 0)
                Ssh[wn][wm * 64 + mi * 16 + (lane >> 4) * 4 + jj] = v;
        }
    if (!diag) {
        #pragma unroll
        for (int nj = 0; nj < 4; ++nj) {
            float v = rs2[nj];
            v += __shfl_xor(v, 16, 64);
            v += __shfl_xor(v, 32, 64);
            if (lane < 16) Ssh2[wm][wn * 64 + nj * 16 + lane] = v;
        }
    }
    __syncthreads();
    if (tid < 128) {
        Sp[(size_t)n * (NB * LP) + (size_t)batch * LP + m0 + tid] =
            Ssh[0][tid] + Ssh[1][tid];
        if (!diag)
            Sp[(size_t)m * (NB * LP) + (size_t)batch * LP + n0 + tid] =
                Ssh2[0][tid] + Ssh2[1][tid];
    }
}

// ---------------- GEMM2 (NT): P2[p][d] = (sum_l E[p][l]*Rt[d][l]) / S[p], bf16 out ----------------
__global__ __launch_bounds__(256) void gemm2_kernel(
    const bf16* __restrict__ E, const bf16* __restrict__ Rt,
    const float* __restrict__ Sp, bf16* __restrict__ P2) {
    __shared__ __align__(128) bf16 As[128 * 64];
    __shared__ __align__(128) bf16 Bs[128 * 64];
    __shared__ float invS[128];
    int tid = threadIdx.x, lane = tid & 63, wave = tid >> 6;
    int wm = wave >> 1, wn = wave & 1;
    const int nwg = NT2 * MT2 * NB;
    int wgid = xcd_wgid(blockIdx.x, nwg);
    int n = wgid % NT2, m = (wgid / NT2) % MT2, batch = wgid / (NT2 * MT2);
    int m0 = m * 128, n0 = n * 128;

    if (tid < 128) {
        float s = 0.f;
        #pragma unroll
        for (int nt = 0; nt < NT1; ++nt)
            s += Sp[(size_t)nt * (NB * LP) + (size_t)batch * LP + m0 + tid];
        invS[tid] = 1.0f / s;
    }

    const char* Ag = (const char*)(E + ((size_t)batch * LP + m0) * LP);
    const char* Bg = (const char*)(Rt + ((size_t)batch * KR + n0) * LP);
    const size_t sLP = (size_t)LP * 2;

    f32x4 acc[4][4] = {};
    for (int k0 = 0; k0 < L; k0 += 64) {
        stage_tile(Ag + (size_t)k0 * 2, sLP, (char*)As, wave, lane);
        stage_tile(Bg + (size_t)k0 * 2, sLP, (char*)Bs, wave, lane);
        __syncthreads();
        #pragma unroll
        for (int h = 0; h < 2; ++h) {
            bfrag af[4], bfv[4];
            #pragma unroll
            for (int mi = 0; mi < 4; ++mi) {
                int r = wm * 64 + mi * 16 + (lane & 15);
                int sl = (h * 4 + (lane >> 4)) ^ (r & 7);
                af[mi] = *(const bfrag*)((const char*)As + r * 128 + sl * 16);
            }
            #pragma unroll
            for (int nj = 0; nj < 4; ++nj) {
                int r = wn * 64 + nj * 16 + (lane & 15);
                int sl = (h * 4 + (lane >> 4)) ^ (r & 7);
                bfv[nj] = *(const bfrag*)((const char*)Bs + r * 128 + sl * 16);
            }
            #pragma unroll
            for (int mi = 0; mi < 4; ++mi)
                #pragma unroll
                for (int nj = 0; nj < 4; ++nj)
                    acc[mi][nj] = __builtin_amdgcn_mfma_f32_16x16x32_bf16(
                        af[mi], bfv[nj], acc[mi][nj], 0, 0, 0);
        }
        __syncthreads();
    }

    bf16* outb = P2 + (size_t)batch * LP * KR;
    #pragma unroll
    for (int nj = 0; nj < 4; ++nj) {
        int d = n0 + wn * 64 + nj * 16 + (lane & 15);
        #pragma unroll
        for (int mi = 0; mi < 4; ++mi)
            #pragma unroll
            for (int jj = 0; jj < 4; ++jj) {
                int pl = wm * 64 + mi * 16 + (lane >> 4) * 4 + jj;
                outb[(size_t)(m0 + pl) * KR + d] =
                    __float2bfloat16(acc[mi][nj][jj] * invS[pl]);
            }
    }
}

// ---------------- fold (overlap-add) + crop + /4 ----------------
__global__ void fold_kernel(const bf16* __restrict__ P2, float* __restrict__ out) {
    size_t idx = (size_t)blockIdx.x * blockDim.x + threadIdx.x;
    if (idx >= (size_t)NB * CCH * H * W_) return;
    int x = (int)(idx % W_);
    int y = (int)((idx / W_) % H);
    int c = (int)((idx / ((size_t)W_ * H)) % CCH);
    int batch = (int)(idx / ((size_t)W_ * H * CCH));
    int yp = y + 1, xp = x + 1;
    float s = 0.f;
    #pragma unroll
    for (int du = 0; du < 2; ++du) {
        int u = (yp & 1) + 2 * du;
        int ph2 = yp - u;
        if (ph2 < 0) continue;
        int ph = ph2 >> 1;
        if (ph >= HS) continue;
        #pragma unroll
        for (int dv = 0; dv < 2; ++dv) {
            int v = (xp & 1) + 2 * dv;
            int pw2 = xp - v;
            if (pw2 < 0) continue;
            int pw = pw2 >> 1;
            if (pw >= HS) continue;
            s += __bfloat162float(
                P2[((size_t)batch * LP + ph * HS + pw) * KR + c * 16 + u * 4 + v]);
        }
    }
    out[idx] = 0.25f * s;
}

extern "C" void kernel_launch(void* const* d_in, const int* in_sizes, int n_in,
                              void* d_out, int out_size, void* d_ws, size_t ws_size,
                              hipStream_t stream) {
    const float* b    = (const float*)d_in[0];
    const float* mask = (const float*)d_in[1];
    float* out = (float*)d_out;

    char* w = (char*)d_ws;
    bf16* Wb = (bf16*)w;  w += (size_t)NB * LP * KD * 2;   // 7.7 MB
    bf16* Rt = (bf16*)w;  w += (size_t)NB * KR * LP * 2;   // 13.6 MB
    bf16* E  = (bf16*)w;  w += (size_t)NB * LP * LP * 2;   // 22.2 MB
    bf16* P2 = (bf16*)w;  w += (size_t)NB * LP * KR * 2;   // 13.6 MB
    float* norms = (float*)w; w += (size_t)NB * LP * 4;
    float* mmv = (float*)w;   w += (size_t)LP * 4;
    float* Sp = (float*)w;    w += (size_t)NT1 * NB * LP * 4;  // 346 KB
    // total ~58 MB

    build_w_kernel<<<NB * LP, KD, 0, stream>>>(b, Wb, norms);
    mm_kernel<<<(LP + 255) / 256, 256, 0, stream>>>(mask, mmv);
    build_rt_kernel<<<NB * KR * (LP / 8) / 256, 256, 0, stream>>>(b, Rt);

    gemm1_kernel<<<NB * NPAIR, 256, 0, stream>>>(Wb, norms, mmv, E, Sp);
    gemm2_kernel<<<NT2 * MT2 * NB, 256, 0, stream>>>(E, Rt, Sp, P2);

    fold_kernel<<<(int)(((size_t)NB * CCH * H * W_ + 255) / 256), 256, 0, stream>>>(P2, out);
}

// Round 5
// 100.823 us; speedup vs baseline: 4.9571x; 1.1460x over previous
//
#include <hip/hip_runtime.h>
#include <hip/hip_bf16.h>

#define L 1600
#define LP 1664          // 13*128 = 26*64
#define CCH 64
#define H 80
#define W_ 80
#define HS 40
#define KD 576           // C*3*3
#define KR 1024          // C*4*4
#define NB 4
#define NT1 13
#define NPAIR 91         // NT1*(NT1+1)/2
#define MT2P 8           // KR/128 (d tiles)
#define NT2P 26          // LP/64  (p tiles)

typedef __hip_bfloat16 bf16;
typedef short bfrag __attribute__((ext_vector_type(8)));
typedef float f32x4 __attribute__((ext_vector_type(4)));
typedef short short4_t __attribute__((ext_vector_type(4)));
typedef short short8_t __attribute__((ext_vector_type(8)));

__device__ __forceinline__ void gload16(const void* g, void* l) {
    __builtin_amdgcn_global_load_lds(
        (const __attribute__((address_space(1))) unsigned int*)g,
        (__attribute__((address_space(3))) unsigned int*)l, 16, 0, 0);
}

// bijective XCD swizzle (m204)
__device__ __forceinline__ int xcd_wgid(int orig, int nwg) {
    int q = nwg >> 3, r = nwg & 7;
    int xcd = orig & 7, iw = orig >> 3;
    return (xcd < r) ? xcd * (q + 1) + iw : r * (q + 1) + (xcd - r) * q + iw;
}

// ---------------- build W (B,LP,576) bf16 + norms (B,LP) ----------------
__global__ void build_w_kernel(const float* __restrict__ b,
                               bf16* __restrict__ Wm,
                               float* __restrict__ norms) {
    int bl = blockIdx.x;
    int batch = bl / LP, l = bl % LP;
    int t = threadIdx.x;               // 0..575
    if (l >= L) {
        Wm[(size_t)bl * KD + t] = __float2bfloat16(0.f);
        if (t == 0) norms[bl] = 1.f;
        return;
    }
    int lh = l / HS, lw = l % HS;
    int c = t / 9, r = t % 9;
    int i = r / 3, j = r % 3;
    int y = lh + i - 1, x = lw + j - 1;
    float v = 0.f;
    if (y >= 0 && y < HS && x >= 0 && x < HS)
        v = b[((size_t)(batch * CCH + c) * H + 2 * y) * W_ + 2 * x];
    Wm[(size_t)bl * KD + t] = __float2bfloat16(v);

    float s = v * v;
    #pragma unroll
    for (int o = 32; o > 0; o >>= 1) s += __shfl_down(s, o, 64);
    __shared__ float ws[9];
    if ((t & 63) == 0) ws[t >> 6] = s;
    __syncthreads();
    if (t == 0) {
        float tot = 0.f;
        #pragma unroll
        for (int w = 0; w < 9; ++w) tot += ws[w];
        norms[bl] = sqrtf(tot);
    }
}

// ---------------- mm (LP) from mask ----------------
__global__ void mm_kernel(const float* __restrict__ mask, float* __restrict__ mmv) {
    int l = blockIdx.x * blockDim.x + threadIdx.x;
    if (l >= LP) return;
    if (l >= L) { mmv[l] = 0.f; return; }
    int lh = l / HS, lw = l % HS;
    float s = 0.f;
    for (int i = 0; i < 3; ++i)
        for (int j = 0; j < 3; ++j) {
            int y = lh + i - 1, x = lw + j - 1;
            if (y >= 0 && y < HS && x >= 0 && x < HS)
                s += mask[(2 * y) * W_ + 2 * x];
        }
    mmv[l] = ((s / 9.0f) == 0.0f) ? 1.f : 0.f;
}

// ---------------- build R transposed: Rt (B,1024,LP) bf16, short8 stores ----------------
__global__ void build_rt_kernel(const float* __restrict__ b, bf16* __restrict__ Rt) {
    int idx = blockIdx.x * 256 + threadIdx.x;      // NB*KR*(LP/8) threads
    int lp = idx % (LP / 8);
    int rest = idx / (LP / 8);
    int d = rest % KR, batch = rest / KR;
    int l8 = lp * 8;
    short8_t pack = {};
    if (l8 < L) {
        int c = d >> 4, u = (d >> 2) & 3, v = d & 3;
        int lh = l8 / HS, lw0 = l8 % HS;           // 8 | 40 -> pack never crosses a row
        int y = 2 * lh + u - 1;
        if (y >= 0 && y < H) {
            const float* row = b + ((size_t)(batch * CCH + c) * H + y) * W_;
            #pragma unroll
            for (int j = 0; j < 8; ++j) {
                int x = 2 * (lw0 + j) + v - 1;
                float val = (x >= 0 && x < W_) ? row[x] : 0.f;
                bf16 hv = __float2bfloat16(val);
                pack[j] = *reinterpret_cast<short*>(&hv);
            }
        }
    }
    *reinterpret_cast<short8_t*>(Rt + ((size_t)batch * KR + d) * LP + l8) = pack;
}

// LDS tile: [ROWS rows][64 bf16 = 8 slots of 16B], slot' = slot ^ (row&7)
template<int ROWS>
__device__ __forceinline__ void stage_tile(const char* gbase, size_t strideB,
                                           char* lds, int wave, int lane) {
    #pragma unroll
    for (int it = 0; it < ROWS / 32; ++it) {
        int cb = it * 256 + wave * 64;
        int c = cb + lane;
        int row = c >> 3, s = c & 7;
        const char* g = gbase + (size_t)row * strideB + ((s ^ (row & 7)) << 4);
        gload16(g, lds + (size_t)cb * 16);
    }
}

// ---------------- GEMM1 triangular (m<=n): one dot -> both E[p][l] and E[l][p] ----------------
__global__ __launch_bounds__(256) void gemm1_kernel(
    const bf16* __restrict__ Wm, const float* __restrict__ norms,
    const float* __restrict__ mmv, bf16* __restrict__ E, float* __restrict__ Sp) {
    __shared__ __align__(128) bf16 smem[2 * 128 * 64];   // As | Bs, reused as T (32KB)
    __shared__ float Ssh[2][128];   // e1 row-sums  [wn][p-idx]
    __shared__ float Ssh2[2][128];  // e2 col-sums  [wm][l-idx]
    bf16* As = smem;
    bf16* Bs = smem + 128 * 64;
    bf16* T  = smem;                // transpose scratch, valid after k-loop
    int tid = threadIdx.x, lane = tid & 63, wave = tid >> 6;
    int wm = wave >> 1, wn = wave & 1;
    const int nwg = NB * NPAIR;
    int wgid = xcd_wgid(blockIdx.x, nwg);
    int batch = wgid / NPAIR;
    int t91 = wgid % NPAIR;
    int m = 0;
    while (t91 >= NT1 - m) { t91 -= NT1 - m; ++m; }
    int n = m + t91;
    bool diag = (m == n);
    int m0 = m * 128, n0 = n * 128;

    const char* Ag = (const char*)(Wm + ((size_t)batch * LP + m0) * KD);
    const char* Bg = (const char*)(Wm + ((size_t)batch * LP + n0) * KD);
    const size_t sKD = (size_t)KD * 2;

    f32x4 acc[4][4] = {};
    for (int k0 = 0; k0 < KD; k0 += 64) {
        stage_tile<128>(Ag + (size_t)k0 * 2, sKD, (char*)As, wave, lane);
        stage_tile<128>(Bg + (size_t)k0 * 2, sKD, (char*)Bs, wave, lane);
        __syncthreads();
        #pragma unroll
        for (int h = 0; h < 2; ++h) {
            bfrag af[4], bfv[4];
            #pragma unroll
            for (int mi = 0; mi < 4; ++mi) {
                int r = wm * 64 + mi * 16 + (lane & 15);
                int sl = (h * 4 + (lane >> 4)) ^ (r & 7);
                af[mi] = *(const bfrag*)((const char*)As + r * 128 + sl * 16);
            }
            #pragma unroll
            for (int nj = 0; nj < 4; ++nj) {
                int r = wn * 64 + nj * 16 + (lane & 15);
                int sl = (h * 4 + (lane >> 4)) ^ (r & 7);
                bfv[nj] = *(const bfrag*)((const char*)Bs + r * 128 + sl * 16);
            }
            #pragma unroll
            for (int mi = 0; mi < 4; ++mi)
                #pragma unroll
                for (int nj = 0; nj < 4; ++nj)
                    acc[mi][nj] = __builtin_amdgcn_mfma_f32_16x16x32_bf16(
                        af[mi], bfv[nj], acc[mi][nj], 0, 0, 0);
        }
        __syncthreads();
    }

    const float* nr = norms + (size_t)batch * LP;
    bf16* Eb = E + (size_t)batch * LP * LP;

    // p-side (row) constants
    float Mp[4][4], scp[4][4], mmp[4][4], vldp[4][4];
    #pragma unroll
    for (int mi = 0; mi < 4; ++mi)
        #pragma unroll
        for (int jj = 0; jj < 4; ++jj) {
            int p = m0 + wm * 64 + mi * 16 + (lane >> 4) * 4 + jj;
            float np = nr[p];
            float mp = mmv[p];
            Mp[mi][jj] = 10.0f * np;
            scp[mi][jj] = 10.0f / fmaxf(np, 1e-4f) * mp;
            mmp[mi][jj] = mp;
            vldp[mi][jj] = (p < L) ? 1.f : 0.f;
        }

    float rs1[4][4] = {};
    float rs2[4] = {};

    #pragma unroll
    for (int nj = 0; nj < 4; ++nj) {
        int l = n0 + wn * 64 + nj * 16 + (lane & 15);
        float nl = nr[l];
        float mml = mmv[l];
        float scl = 10.0f / fmaxf(nl, 1e-4f) * mml;
        float Ml = 10.0f * nl;
        float vldl = (l < L) ? 1.f : 0.f;
        #pragma unroll
        for (int mi = 0; mi < 4; ++mi) {
            short4_t pk = {};
            #pragma unroll
            for (int jj = 0; jj < 4; ++jj) {
                float dotv = acc[mi][nj][jj];
                int p = m0 + wm * 64 + mi * 16 + (lane >> 4) * 4 + jj;
                float e1 = __expf(dotv * scl - Mp[mi][jj]);
                rs1[mi][jj] += e1 * vldl;
                Eb[(size_t)p * LP + l] = __float2bfloat16(e1 * mml);
                if (!diag) {
                    float e2 = __expf(dotv * scp[mi][jj] - Ml);
                    rs2[nj] += e2 * vldp[mi][jj];
                    bf16 hv = __float2bfloat16(e2 * mmp[mi][jj]);
                    pk[jj] = *reinterpret_cast<short*>(&hv);
                }
            }
            if (!diag) {
                // stage transposed tile into LDS (swizzled), coalesced write-out later
                int l_local = wn * 64 + nj * 16 + (lane & 15);
                int p_base  = wm * 64 + mi * 16 + (lane >> 4) * 4;
                int slot = (p_base >> 3) ^ (l_local & 7);
                *(short4_t*)((char*)T + l_local * 256 + slot * 16 + (p_base & 7) * 2) = pk;
            }
        }
    }

    #pragma unroll
    for (int mi = 0; mi < 4; ++mi)
        #pragma unroll
        for (int jj = 0; jj < 4; ++jj) {
            float v = rs1[mi][jj];
            v += __shfl_xor(v, 1, 64);
            v += __shfl_xor(v, 2, 64);
            v += __shfl_xor(v, 4, 64);
            v += __shfl_xor(v, 8, 64);
            if ((lane & 15) == 0)
                Ssh[wn][wm * 64 + mi * 16 + (lane >> 4) * 4 + jj] = v;
        }
    if (!diag) {
        #pragma unroll
        for (int nj = 0; nj < 4; ++nj) {
            float v = rs2[nj];
            v += __shfl_xor(v, 16, 64);
            v += __shfl_xor(v, 32, 64);
            if (lane < 16) Ssh2[wm][wn * 64 + nj * 16 + lane] = v;
        }
    }
    __syncthreads();
    if (tid < 128) {
        Sp[(size_t)n * (NB * LP) + (size_t)batch * LP + m0 + tid] =
            Ssh[0][tid] + Ssh[1][tid];
        if (!diag)
            Sp[(size_t)m * (NB * LP) + (size_t)batch * LP + n0 + tid] =
                Ssh2[0][tid] + Ssh2[1][tid];
    }
    if (!diag) {
        // coalesced write-out of transposed tile: rows l (n-tile), cols p (m-tile)
        #pragma unroll
        for (int it = 0; it < 8; ++it) {
            int row = it * 16 + (tid >> 4);
            int col16 = tid & 15;
            int slot = col16 ^ (row & 7);
            short8_t v = *(const short8_t*)((const char*)T + row * 256 + slot * 16);
            *(short8_t*)(Eb + (size_t)(n0 + row) * LP + m0 + col16 * 8) = v;
        }
    }
}

// ---------------- GEMM2 (NT, transposed out): P2t[d][p] = (sum_l Rt[d][l]*E[p][l]) / S[p] ----------------
__global__ __launch_bounds__(256) void gemm2_kernel(
    const bf16* __restrict__ E, const bf16* __restrict__ Rt,
    const float* __restrict__ Sp, bf16* __restrict__ P2t) {
    __shared__ __align__(128) bf16 As[128 * 64];   // Rt tile (d-rows)
    __shared__ __align__(128) bf16 Bs[64 * 64];    // E tile (p-rows)
    __shared__ float invS[64];
    int tid = threadIdx.x, lane = tid & 63, wave = tid >> 6;
    int wm = wave >> 1, wn = wave & 1;
    const int nwg = NB * NT2P * MT2P;
    int wgid = xcd_wgid(blockIdx.x, nwg);
    int m = wgid % MT2P;                 // d tile (fastest: Rt streams, E panel held)
    int n = (wgid / MT2P) % NT2P;        // p tile
    int batch = wgid / (MT2P * NT2P);
    int m0 = m * 128, n0 = n * 64;

    if (tid < 64) {
        float s = 0.f;
        #pragma unroll
        for (int nt = 0; nt < NT1; ++nt)
            s += Sp[(size_t)nt * (NB * LP) + (size_t)batch * LP + n0 + tid];
        invS[tid] = 1.0f / s;
    }

    const char* Ag = (const char*)(Rt + ((size_t)batch * KR + m0) * LP);
    const char* Bg = (const char*)(E + ((size_t)batch * LP + n0) * LP);
    const size_t sLP = (size_t)LP * 2;

    f32x4 acc[4][2] = {};
    for (int k0 = 0; k0 < L; k0 += 64) {
        stage_tile<128>(Ag + (size_t)k0 * 2, sLP, (char*)As, wave, lane);
        stage_tile<64>(Bg + (size_t)k0 * 2, sLP, (char*)Bs, wave, lane);
        __syncthreads();
        #pragma unroll
        for (int h = 0; h < 2; ++h) {
            bfrag af[4], bfv[2];
            #pragma unroll
            for (int mi = 0; mi < 4; ++mi) {
                int r = wm * 64 + mi * 16 + (lane & 15);
                int sl = (h * 4 + (lane >> 4)) ^ (r & 7);
                af[mi] = *(const bfrag*)((const char*)As + r * 128 + sl * 16);
            }
            #pragma unroll
            for (int nj = 0; nj < 2; ++nj) {
                int r = wn * 32 + nj * 16 + (lane & 15);
                int sl = (h * 4 + (lane >> 4)) ^ (r & 7);
                bfv[nj] = *(const bfrag*)((const char*)Bs + r * 128 + sl * 16);
            }
            #pragma unroll
            for (int mi = 0; mi < 4; ++mi)
                #pragma unroll
                for (int nj = 0; nj < 2; ++nj)
                    acc[mi][nj] = __builtin_amdgcn_mfma_f32_16x16x32_bf16(
                        af[mi], bfv[nj], acc[mi][nj], 0, 0, 0);
        }
        __syncthreads();
    }

    bf16* outb = P2t + (size_t)batch * KR * LP;
    #pragma unroll
    for (int nj = 0; nj < 2; ++nj) {
        int pl = wn * 32 + nj * 16 + (lane & 15);   // local p (col)
        float is = invS[pl];
        #pragma unroll
        for (int mi = 0; mi < 4; ++mi)
            #pragma unroll
            for (int jj = 0; jj < 4; ++jj) {
                int d = m0 + wm * 64 + mi * 16 + (lane >> 4) * 4 + jj;
                outb[(size_t)d * LP + n0 + pl] =
                    __float2bfloat16(acc[mi][nj][jj] * is);
            }
    }
}

// ---------------- fold (overlap-add) + crop + /4, reading P2t[d][p] ----------------
__global__ void fold_kernel(const bf16* __restrict__ P2t, float* __restrict__ out) {
    size_t idx = (size_t)blockIdx.x * blockDim.x + threadIdx.x;
    if (idx >= (size_t)NB * CCH * H * W_) return;
    int x = (int)(idx % W_);
    int y = (int)((idx / W_) % H);
    int c = (int)((idx / ((size_t)W_ * H)) % CCH);
    int batch = (int)(idx / ((size_t)W_ * H * CCH));
    int yp = y + 1, xp = x + 1;
    float s = 0.f;
    #pragma unroll
    for (int du = 0; du < 2; ++du) {
        int u = (yp & 1) + 2 * du;
        int ph2 = yp - u;
        if (ph2 < 0) continue;
        int ph = ph2 >> 1;
        if (ph >= HS) continue;
        #pragma unroll
        for (int dv = 0; dv < 2; ++dv) {
            int v = (xp & 1) + 2 * dv;
            int pw2 = xp - v;
            if (pw2 < 0) continue;
            int pw = pw2 >> 1;
            if (pw >= HS) continue;
            s += __bfloat162float(
                P2t[((size_t)batch * KR + c * 16 + u * 4 + v) * LP + ph * HS + pw]);
        }
    }
    out[idx] = 0.25f * s;
}

extern "C" void kernel_launch(void* const* d_in, const int* in_sizes, int n_in,
                              void* d_out, int out_size, void* d_ws, size_t ws_size,
                              hipStream_t stream) {
    const float* b    = (const float*)d_in[0];
    const float* mask = (const float*)d_in[1];
    float* out = (float*)d_out;

    char* w = (char*)d_ws;
    bf16* Wb = (bf16*)w;  w += (size_t)NB * LP * KD * 2;   // 7.7 MB
    bf16* Rt = (bf16*)w;  w += (size_t)NB * KR * LP * 2;   // 13.6 MB
    bf16* E  = (bf16*)w;  w += (size_t)NB * LP * LP * 2;   // 22.2 MB
    bf16* P2t = (bf16*)w; w += (size_t)NB * KR * LP * 2;   // 13.6 MB
    float* norms = (float*)w; w += (size_t)NB * LP * 4;
    float* mmv = (float*)w;   w += (size_t)LP * 4;
    float* Sp = (float*)w;    w += (size_t)NT1 * NB * LP * 4;  // 346 KB
    // total ~58 MB

    build_w_kernel<<<NB * LP, KD, 0, stream>>>(b, Wb, norms);
    mm_kernel<<<(LP + 255) / 256, 256, 0, stream>>>(mask, mmv);
    build_rt_kernel<<<NB * KR * (LP / 8) / 256, 256, 0, stream>>>(b, Rt);

    gemm1_kernel<<<NB * NPAIR, 256, 0, stream>>>(Wb, norms, mmv, E, Sp);
    gemm2_kernel<<<NB * NT2P * MT2P, 256, 0, stream>>>(E, Rt, Sp, P2t);

    fold_kernel<<<(int)(((size_t)NB * CCH * H * W_ + 255) / 256), 256, 0, stream>>>(P2t, out);
}